// Round 1
// baseline (137.023 us; speedup 1.0000x reference)
//
#include <hip/hip_runtime.h>

#define N_ROWS 4096
#define TN 8192      // 2N
#define DIM 128
#define INV_T 10.0f

#define BM 64        // rows per block in main kernel
#define COLSPLIT 16  // grid.y col chunks
#define Z_BYTE_OFF 36864  // z (bf16) offset in ws; [0,8192) f32 denom, [8192] f32 pos

typedef __attribute__((ext_vector_type(8))) short short8;
typedef __attribute__((ext_vector_type(4))) float f32x4;

static __device__ __forceinline__ ushort f2bf(float f) {
    union { float f; unsigned u; } a; a.f = f;
    unsigned r = a.u + 0x7FFF + ((a.u >> 16) & 1);  // round-to-nearest-even
    return (ushort)(r >> 16);
}

// --- Kernel A: L2-normalize rows of [anchor; target] -> bf16 z[8192][128] ---
__global__ __launch_bounds__(256) void normalize_kernel(
    const float* __restrict__ anchor, const float* __restrict__ target,
    ushort* __restrict__ z)
{
    int row  = blockIdx.x * 4 + (threadIdx.x >> 6);
    int lane = threadIdx.x & 63;
    const float* src = (row < N_ROWS) ? (anchor + (size_t)row * DIM)
                                      : (target + (size_t)(row - N_ROWS) * DIM);
    float2 v = ((const float2*)src)[lane];
    float ss = v.x * v.x + v.y * v.y;
    #pragma unroll
    for (int m = 1; m < 64; m <<= 1) ss += __shfl_xor(ss, m, 64);
    float r = rsqrtf(fmaxf(ss, 1e-12f));
    ushort2 st;
    st.x = f2bf(v.x * r);
    st.y = f2bf(v.y * r);
    ((ushort2*)(z + (size_t)row * DIM))[lane] = st;
}

// --- Kernel B: positives_i = cos(a_i, t_i) in fp32, accumulated ---
__global__ __launch_bounds__(256) void positives_kernel(
    const float* __restrict__ anchor, const float* __restrict__ target,
    float* __restrict__ pos_accum)
{
    int i    = blockIdx.x * 4 + (threadIdx.x >> 6);
    int wave = threadIdx.x >> 6;
    int lane = threadIdx.x & 63;
    float2 a = ((const float2*)(anchor + (size_t)i * DIM))[lane];
    float2 t = ((const float2*)(target + (size_t)i * DIM))[lane];
    float sa = a.x * a.x + a.y * a.y;
    float st = t.x * t.x + t.y * t.y;
    float dt = a.x * t.x + a.y * t.y;
    #pragma unroll
    for (int m = 1; m < 64; m <<= 1) {
        sa += __shfl_xor(sa, m, 64);
        st += __shfl_xor(st, m, 64);
        dt += __shfl_xor(dt, m, 64);
    }
    __shared__ float posred[4];
    if (lane == 0) {
        posred[wave] = dt * rsqrtf(fmaxf(sa, 1e-12f)) * rsqrtf(fmaxf(st, 1e-12f));
    }
    __syncthreads();
    if (threadIdx.x == 0)
        atomicAdd(pos_accum, posred[0] + posred[1] + posred[2] + posred[3]);
}

// --- Kernel C: denom_i += sum_{j in col chunk, j!=i} exp(10 * z_i . z_j) ---
__global__ __launch_bounds__(256) void simgemm_kernel(
    const ushort* __restrict__ z, float* __restrict__ denom)
{
    int wave = threadIdx.x >> 6;
    int lane = threadIdx.x & 63;
    int r = lane & 15;       // C col within tile; also A/B row index
    int g = lane >> 4;       // k-group / C row group
    int rowbase = blockIdx.x * BM;
    int colbase = blockIdx.y * (TN / COLSPLIT) + wave * 128;

    // A fragments: 64 rows x 128 k, resident in VGPRs (32 regs-worth/lane x4)
    short8 a[4][4];
    #pragma unroll
    for (int rt = 0; rt < 4; ++rt)
        #pragma unroll
        for (int kt = 0; kt < 4; ++kt)
            a[rt][kt] = *(const short8*)(z + (size_t)(rowbase + rt * 16 + r) * DIM
                                           + kt * 32 + g * 8);

    float ps[4][4];
    #pragma unroll
    for (int rt = 0; rt < 4; ++rt)
        #pragma unroll
        for (int q = 0; q < 4; ++q) ps[rt][q] = 0.0f;

    for (int ct = 0; ct < 8; ++ct) {
        int c0 = colbase + ct * 16;
        short8 b[4];
        #pragma unroll
        for (int kt = 0; kt < 4; ++kt)
            b[kt] = *(const short8*)(z + (size_t)(c0 + r) * DIM + kt * 32 + g * 8);
        int gcol = c0 + r;
        #pragma unroll
        for (int rt = 0; rt < 4; ++rt) {
            f32x4 acc = {0.0f, 0.0f, 0.0f, 0.0f};
            #pragma unroll
            for (int kt = 0; kt < 4; ++kt)
                acc = __builtin_amdgcn_mfma_f32_16x16x32_bf16(a[rt][kt], b[kt], acc, 0, 0, 0);
            #pragma unroll
            for (int q = 0; q < 4; ++q) {
                int grow = rowbase + rt * 16 + g * 4 + q;  // verified C/D layout (m89)
                float e = (grow == gcol) ? 0.0f : __expf(acc[q] * INV_T);
                ps[rt][q] += e;
            }
        }
    }

    // reduce over the 16 lanes sharing g (cols within tile), then one atomic/row
    #pragma unroll
    for (int rt = 0; rt < 4; ++rt)
        #pragma unroll
        for (int q = 0; q < 4; ++q) {
            float v = ps[rt][q];
            v += __shfl_xor(v, 1, 64);
            v += __shfl_xor(v, 2, 64);
            v += __shfl_xor(v, 4, 64);
            v += __shfl_xor(v, 8, 64);
            if (r == 0)
                atomicAdd(&denom[rowbase + rt * 16 + g * 4 + q], v);
        }
}

// --- Kernel D: loss = (sum_i log denom_i - 2*pos_accum/T) / 2N ---
__global__ __launch_bounds__(1024) void finalize_kernel(
    const float* __restrict__ denom, const float* __restrict__ pos_accum,
    float* __restrict__ out)
{
    int tid = threadIdx.x;
    float s = 0.0f;
    #pragma unroll
    for (int u = 0; u < TN / 1024; ++u) s += logf(denom[u * 1024 + tid]);
    #pragma unroll
    for (int m = 1; m < 64; m <<= 1) s += __shfl_xor(s, m, 64);
    __shared__ float red[16];
    if ((tid & 63) == 0) red[tid >> 6] = s;
    __syncthreads();
    if (tid == 0) {
        float tot = 0.0f;
        #pragma unroll
        for (int i = 0; i < 16; ++i) tot += red[i];
        out[0] = (tot - 2.0f * INV_T * pos_accum[0]) / (float)TN;
    }
}

extern "C" void kernel_launch(void* const* d_in, const int* in_sizes, int n_in,
                              void* d_out, int out_size, void* d_ws, size_t ws_size,
                              hipStream_t stream) {
    const float* anchor = (const float*)d_in[0];
    const float* target = (const float*)d_in[1];
    float* denom     = (float*)d_ws;
    float* pos_accum = denom + TN;
    ushort* z        = (ushort*)((char*)d_ws + Z_BYTE_OFF);

    hipMemsetAsync(d_ws, 0, (TN + 8) * sizeof(float), stream);
    normalize_kernel<<<TN / 4, 256, 0, stream>>>(anchor, target, z);
    positives_kernel<<<N_ROWS / 4, 256, 0, stream>>>(anchor, target, pos_accum);
    simgemm_kernel<<<dim3(TN / BM, COLSPLIT), 256, 0, stream>>>(z, denom);
    finalize_kernel<<<1, 1024, 0, stream>>>(denom, pos_accum, (float*)d_out);
}

// Round 2
// 113.493 us; speedup vs baseline: 1.2073x; 1.2073x over previous
//
#include <hip/hip_runtime.h>

#define N_ROWS 4096
#define TN 8192      // 2N
#define DIM 128
#define LOG2E10 14.426950408889634f   // 10 * log2(e); exp(10*s) = exp2(s * LOG2E10)

#define Z_BYTE_OFF 36864  // ws layout: [0,8192) f32 denom, [8192] f32 pos, z bf16 at 36864

typedef __attribute__((ext_vector_type(8))) short short8;
typedef __attribute__((ext_vector_type(4))) float f32x4;

static __device__ __forceinline__ ushort f2bf(float f) {
    union { float f; unsigned u; } a; a.f = f;
    unsigned r = a.u + 0x7FFF + ((a.u >> 16) & 1);  // round-to-nearest-even
    return (ushort)(r >> 16);
}

// --- Kernel A: normalize rows -> bf16 z[8192][128], and positives accum (fused) ---
__global__ __launch_bounds__(256) void prep_kernel(
    const float* __restrict__ anchor, const float* __restrict__ target,
    ushort* __restrict__ z, float* __restrict__ pos_accum)
{
    int wave = threadIdx.x >> 6;
    int lane = threadIdx.x & 63;
    int i    = blockIdx.x * 4 + wave;
    float2 a = ((const float2*)(anchor + (size_t)i * DIM))[lane];
    float2 t = ((const float2*)(target + (size_t)i * DIM))[lane];
    float sa = a.x * a.x + a.y * a.y;
    float st = t.x * t.x + t.y * t.y;
    float dt = a.x * t.x + a.y * t.y;
    #pragma unroll
    for (int m = 1; m < 64; m <<= 1) {
        sa += __shfl_xor(sa, m, 64);
        st += __shfl_xor(st, m, 64);
        dt += __shfl_xor(dt, m, 64);
    }
    float rsa = rsqrtf(fmaxf(sa, 1e-12f));
    float rst = rsqrtf(fmaxf(st, 1e-12f));
    ushort2 za, zt;
    za.x = f2bf(a.x * rsa); za.y = f2bf(a.y * rsa);
    zt.x = f2bf(t.x * rst); zt.y = f2bf(t.y * rst);
    ((ushort2*)(z + (size_t)i * DIM))[lane] = za;
    ((ushort2*)(z + (size_t)(i + N_ROWS) * DIM))[lane] = zt;
    __shared__ float red[4];
    if (lane == 0) red[wave] = dt * rsa * rst;
    __syncthreads();
    if (threadIdx.x == 0)
        atomicAdd(pos_accum, red[0] + red[1] + red[2] + red[3]);
}

// --- Kernel B: denom_i += sum_{j in chunk, j!=i} exp(10 * z_i . z_j) ---
// Block: 128 rows x 1024 cols. 4 waves as 2x2: wave owns 64 rows x 512 cols.
// A (64 rows x 128 k) resident in VGPRs; B streamed from L2 with register
// ping-pong double-buffering, 16-col tiles, 16x16x32 bf16 MFMA.
__global__ __launch_bounds__(256) void simgemm_kernel(
    const ushort* __restrict__ z, float* __restrict__ denom)
{
    int wave = threadIdx.x >> 6;
    int lane = threadIdx.x & 63;
    int r = lane & 15;       // A/B row-within-tile; C col
    int g = lane >> 4;       // k-group; C row group
    int wr = wave >> 1, wc = wave & 1;
    int rowbase = blockIdx.x * 128 + wr * 64;
    int wcol    = blockIdx.y * 1024 + wc * 512;

    // A fragments: 64 rows x 128 k resident (64 VGPRs)
    short8 a[4][4];
    #pragma unroll
    for (int rt = 0; rt < 4; ++rt)
        #pragma unroll
        for (int kt = 0; kt < 4; ++kt)
            a[rt][kt] = *(const short8*)(z + (size_t)(rowbase + rt * 16 + r) * DIM
                                           + kt * 32 + g * 8);

    float ps[4][4];
    #pragma unroll
    for (int rt = 0; rt < 4; ++rt)
        #pragma unroll
        for (int q = 0; q < 4; ++q) ps[rt][q] = 0.0f;

    // wave-uniform: does this wave's 64-row range fall inside its 512-col range?
    bool wavediag = ((unsigned)(rowbase - wcol) < 512u);

    const ushort* pb = z + (size_t)(wcol + r) * DIM + g * 8;

#define LOADB(buf, ptr)                                \
    {   buf[0] = *(const short8*)(ptr);                \
        buf[1] = *(const short8*)((ptr) + 32);         \
        buf[2] = *(const short8*)((ptr) + 64);         \
        buf[3] = *(const short8*)((ptr) + 96); }

#define COMPUTE(ct, b)                                                        \
    {   int c0 = wcol + (ct) * 16;                                            \
        bool dtile = wavediag && ((unsigned)(c0 - rowbase) < 64u);            \
        if (!dtile) {                                                         \
            _Pragma("unroll")                                                 \
            for (int rt = 0; rt < 4; ++rt) {                                  \
                f32x4 acc = {0.f, 0.f, 0.f, 0.f};                             \
                _Pragma("unroll")                                             \
                for (int kt = 0; kt < 4; ++kt)                                \
                    acc = __builtin_amdgcn_mfma_f32_16x16x32_bf16(            \
                        a[rt][kt], b[kt], acc, 0, 0, 0);                      \
                _Pragma("unroll")                                             \
                for (int q = 0; q < 4; ++q)                                   \
                    ps[rt][q] += exp2f(acc[q] * LOG2E10);                     \
            }                                                                 \
        } else {                                                              \
            int gcol = c0 + r;                                                \
            _Pragma("unroll")                                                 \
            for (int rt = 0; rt < 4; ++rt) {                                  \
                f32x4 acc = {0.f, 0.f, 0.f, 0.f};                             \
                _Pragma("unroll")                                             \
                for (int kt = 0; kt < 4; ++kt)                                \
                    acc = __builtin_amdgcn_mfma_f32_16x16x32_bf16(            \
                        a[rt][kt], b[kt], acc, 0, 0, 0);                      \
                _Pragma("unroll")                                             \
                for (int q = 0; q < 4; ++q) {                                 \
                    float e = exp2f(acc[q] * LOG2E10);                        \
                    int grow = rowbase + rt * 16 + g * 4 + q;                 \
                    ps[rt][q] += (grow == gcol) ? 0.0f : e;                   \
                }                                                             \
            }                                                                 \
        } }

    short8 b0[4], b1[4];
    LOADB(b0, pb);
    for (int ct = 0; ct < 32; ct += 2) {
        const ushort* pn = pb + (ct + 1) * (16 * DIM);
        LOADB(b1, pn);                       // prefetch odd tile
        COMPUTE(ct, b0);                     // compute even tile
        if (ct + 2 < 32) {
            const ushort* pn2 = pb + (ct + 2) * (16 * DIM);
            LOADB(b0, pn2);                  // prefetch next even tile
        }
        COMPUTE(ct + 1, b1);                 // compute odd tile
    }
#undef LOADB
#undef COMPUTE

    // reduce across the 16 lanes sharing g, then one atomic per row
    #pragma unroll
    for (int rt = 0; rt < 4; ++rt)
        #pragma unroll
        for (int q = 0; q < 4; ++q) {
            float v = ps[rt][q];
            v += __shfl_xor(v, 1, 64);
            v += __shfl_xor(v, 2, 64);
            v += __shfl_xor(v, 4, 64);
            v += __shfl_xor(v, 8, 64);
            if (r == 0)
                atomicAdd(&denom[rowbase + rt * 16 + g * 4 + q], v);
        }
}

// --- Kernel C: loss = (sum_i log denom_i - 2*pos_accum*10) / 2N ---
__global__ __launch_bounds__(1024) void finalize_kernel(
    const float* __restrict__ denom, const float* __restrict__ pos_accum,
    float* __restrict__ out)
{
    int tid = threadIdx.x;
    float s = 0.0f;
    #pragma unroll
    for (int u = 0; u < TN / 1024; ++u) s += logf(denom[u * 1024 + tid]);
    #pragma unroll
    for (int m = 1; m < 64; m <<= 1) s += __shfl_xor(s, m, 64);
    __shared__ float red[16];
    if ((tid & 63) == 0) red[tid >> 6] = s;
    __syncthreads();
    if (tid == 0) {
        float tot = 0.0f;
        #pragma unroll
        for (int i = 0; i < 16; ++i) tot += red[i];
        out[0] = (tot - 20.0f * pos_accum[0]) / (float)TN;
    }
}

extern "C" void kernel_launch(void* const* d_in, const int* in_sizes, int n_in,
                              void* d_out, int out_size, void* d_ws, size_t ws_size,
                              hipStream_t stream) {
    const float* anchor = (const float*)d_in[0];
    const float* target = (const float*)d_in[1];
    float* denom     = (float*)d_ws;
    float* pos_accum = denom + TN;
    ushort* z        = (ushort*)((char*)d_ws + Z_BYTE_OFF);

    hipMemsetAsync(d_ws, 0, (TN + 8) * sizeof(float), stream);
    prep_kernel<<<N_ROWS / 4, 256, 0, stream>>>(anchor, target, z, pos_accum);
    simgemm_kernel<<<dim3(TN / 128, 8), 256, 0, stream>>>(z, denom);
    finalize_kernel<<<1, 1024, 0, stream>>>(denom, pos_accum, (float*)d_out);
}